// Round 1
// 855.796 us; speedup vs baseline: 1.0253x; 1.0253x over previous
//
#include <hip/hip_runtime.h>
#include <math.h>

#define BB 8
#define SS 4096
#define DD 1024

typedef __attribute__((ext_vector_type(8))) short short8;   // 8 bf16 (4 VGPRs)
typedef __attribute__((ext_vector_type(4))) float f32x4;    // MFMA C/D

// ---------------- bf16 helpers (manual RNE) ----------------
__device__ __forceinline__ unsigned short f2bf(float x) {
    unsigned int u = __float_as_uint(x);
    u += 0x7fffu + ((u >> 16) & 1u);
    return (unsigned short)(u >> 16);
}

// ---------------- async global->LDS, 16B per lane ----------------
__device__ __forceinline__ void gld16(const unsigned short* g, unsigned short* l) {
    __builtin_amdgcn_global_load_lds(
        (const __attribute__((address_space(1))) void*)g,
        (__attribute__((address_space(3))) void*)l,
        16, 0, 0);
}

// XOR swizzle: which 8-elem k-slot of a row lives at LDS slot position p.
// slot' = p ^ ((row ^ (row>>2)) & 3)  -> 8-lane groups of a ds_read_b128 hit
// 8 distinct 16B bank cells (2-way on 16B granularity = free).
__device__ __forceinline__ int swz(int row) { return (row ^ (row >> 2)) & 3; }

// ---------------------------------------------------------------------------
// OLD 128x128 core (kept for scores_bf16): C += A[m,k]*B[n,k], BK=32.
// ---------------------------------------------------------------------------
__device__ __forceinline__ void gemm_core1(
    const unsigned short* __restrict__ Ag, const unsigned short* __restrict__ Bg,
    int lda, int ldb, int K, long m0, long n0,
    unsigned short* As, unsigned short* Bs, f32x4 (&acc)[4][4])
{
    const int t = threadIdx.x;
    const int wave = t >> 6, lane = t & 63;
    const int wm = (wave & 1) * 64, wn = (wave >> 1) * 64;
    const int quad = lane >> 4, l16 = lane & 15;
    const int lr = lane >> 2;            // staging row within 16
    const int lc = (lane & 3) * 8;       // staging k-offset (elements)
    const int ar0 = wave * 32;           // chunk rows staged by this wave

    for (int k0 = 0; k0 < K; k0 += 32) {
        const size_t ga0 = (size_t)(m0 + ar0 + lr) * lda + k0 + lc;
        const size_t ga1 = ga0 + (size_t)16 * lda;
        const size_t gb0 = (size_t)(n0 + ar0 + lr) * ldb + k0 + lc;
        const size_t gb1 = gb0 + (size_t)16 * ldb;
        gld16(Ag + ga0, As + ar0 * 32);
        gld16(Ag + ga1, As + (ar0 + 16) * 32);
        gld16(Bg + gb0, Bs + ar0 * 32);
        gld16(Bg + gb1, Bs + (ar0 + 16) * 32);
        __syncthreads();

        short8 a[4], b[4];
        #pragma unroll
        for (int i = 0; i < 4; ++i) {
            a[i] = *(const short8*)&As[(wm + i * 16 + l16) * 32 + quad * 8];
            b[i] = *(const short8*)&Bs[(wn + i * 16 + l16) * 32 + quad * 8];
        }
        #pragma unroll
        for (int i = 0; i < 4; ++i)
            #pragma unroll
            for (int j = 0; j < 4; ++j)
                acc[i][j] = __builtin_amdgcn_mfma_f32_16x16x32_bf16(a[i], b[j], acc[i][j], 0, 0, 0);
        __syncthreads();
    }
}

// ---------------------------------------------------------------------------
// NEW 256x256 core: BK=32, 512 thr = 8 waves (2M x 4N), per-wave 128x64 out.
// 4-deep circular LDS (4 x 16KB per operand = 128 KiB total), counted vmcnt(8)
// (never drained in main loop), 1 barrier/K-step, 4 interleaved sub-phases,
// XOR bank swizzle applied source-side (gld_lds dest stays linear).
// ---------------------------------------------------------------------------
__device__ __forceinline__ void gemm_core256(
    const unsigned short* __restrict__ Ag, const unsigned short* __restrict__ Bg,
    int lda, int ldb, int K, long m0, long n0,
    unsigned short* As, unsigned short* Bs, f32x4 (&acc)[8][4])
{
    const int t = threadIdx.x;
    const int wave = t >> 6, lane = t & 63;
    const int wm = (wave >> 2) * 128, wn = (wave & 3) * 64;
    const int quad = lane >> 4, l16 = lane & 15;

    // ---- staging geometry (fixed per lane): rows [0,128) and [128,256) ----
    const int srow0 = (wave << 4) + (lane >> 2);
    const int srow1 = srow0 + 128;
    const int sslot = lane & 3;
    const size_t gA0 = (size_t)(m0 + srow0) * lda + (size_t)((sslot ^ swz(srow0)) * 8);
    const size_t gA1 = (size_t)(m0 + srow1) * lda + (size_t)((sslot ^ swz(srow1)) * 8);
    const size_t gB0 = (size_t)(n0 + srow0) * ldb + (size_t)((sslot ^ swz(srow0)) * 8);
    const size_t gB1 = (size_t)(n0 + srow1) * ldb + (size_t)((sslot ^ swz(srow1)) * 8);
    const int lA0 = (wave << 4) * 32;          // wave-uniform LDS elem base
    const int lA1 = lA0 + 128 * 32;

    // ---- fragment read offsets (elements, swizzled) ----
    int aoff[8], boff[4];
    #pragma unroll
    for (int i = 0; i < 8; ++i) {
        const int r = wm + i * 16 + l16;
        aoff[i] = r * 32 + ((quad ^ swz(r)) << 3);
    }
    #pragma unroll
    for (int j = 0; j < 4; ++j) {
        const int r = wn + j * 16 + l16;
        boff[j] = r * 32 + ((quad ^ swz(r)) << 3);
    }

    const int NT = K >> 5;

    // ---- prologue: stage tiles 0..2 (12 loads in flight) ----
    #pragma unroll
    for (int tt = 0; tt < 3; ++tt) {
        if (tt < NT) {
            gld16(Ag + gA0 + (size_t)tt * 32, As + tt * 8192 + lA0);
            gld16(Ag + gA1 + (size_t)tt * 32, As + tt * 8192 + lA1);
            gld16(Bg + gB0 + (size_t)tt * 32, Bs + tt * 8192 + lA0);
            gld16(Bg + gB1 + (size_t)tt * 32, Bs + tt * 8192 + lA1);
        }
    }

    for (int tk = 0; tk < NT; ++tk) {
        // counted wait: own tile-tk loads forced complete; tiles tk+1, tk+2
        // (8 loads) stay in flight across the barrier. Epilogue drains 8->4->0.
        if (tk < NT - 2)       asm volatile("s_waitcnt vmcnt(8)" ::: "memory");
        else if (tk == NT - 2) asm volatile("s_waitcnt vmcnt(4)" ::: "memory");
        else                   asm volatile("s_waitcnt vmcnt(0)" ::: "memory");
        __builtin_amdgcn_s_barrier();
        asm volatile("" ::: "memory");   // keep ds_reads below the barrier

        const int cb = tk & 3;
        const int pf = tk + 3;
        const int pb = pf & 3;
        const bool dopf = pf < NT;
        const unsigned short* Ac = As + cb * 8192;
        const unsigned short* Bc = Bs + cb * 8192;
        unsigned short* Asw = As + pb * 8192;
        unsigned short* Bsw = Bs + pb * 8192;

        short8 bb0 = *(const short8*)&Bc[boff[0]];
        short8 bb1 = *(const short8*)&Bc[boff[1]];
        short8 bb2 = *(const short8*)&Bc[boff[2]];
        short8 bb3 = *(const short8*)&Bc[boff[3]];

        #pragma unroll
        for (int q = 0; q < 4; ++q) {
            short8 a0 = *(const short8*)&Ac[aoff[2 * q]];
            short8 a1 = *(const short8*)&Ac[aoff[2 * q + 1]];
            if (dopf) {
                if (q == 0)      gld16(Ag + gA0 + (size_t)pf * 32, Asw + lA0);
                else if (q == 1) gld16(Ag + gA1 + (size_t)pf * 32, Asw + lA1);
                else if (q == 2) gld16(Bg + gB0 + (size_t)pf * 32, Bsw + lA0);
                else             gld16(Bg + gB1 + (size_t)pf * 32, Bsw + lA1);
            }
            __builtin_amdgcn_s_setprio(1);
            acc[2*q][0]   = __builtin_amdgcn_mfma_f32_16x16x32_bf16(a0, bb0, acc[2*q][0],   0, 0, 0);
            acc[2*q+1][0] = __builtin_amdgcn_mfma_f32_16x16x32_bf16(a1, bb0, acc[2*q+1][0], 0, 0, 0);
            acc[2*q][1]   = __builtin_amdgcn_mfma_f32_16x16x32_bf16(a0, bb1, acc[2*q][1],   0, 0, 0);
            acc[2*q+1][1] = __builtin_amdgcn_mfma_f32_16x16x32_bf16(a1, bb1, acc[2*q+1][1], 0, 0, 0);
            acc[2*q][2]   = __builtin_amdgcn_mfma_f32_16x16x32_bf16(a0, bb2, acc[2*q][2],   0, 0, 0);
            acc[2*q+1][2] = __builtin_amdgcn_mfma_f32_16x16x32_bf16(a1, bb2, acc[2*q+1][2], 0, 0, 0);
            acc[2*q][3]   = __builtin_amdgcn_mfma_f32_16x16x32_bf16(a0, bb3, acc[2*q][3],   0, 0, 0);
            acc[2*q+1][3] = __builtin_amdgcn_mfma_f32_16x16x32_bf16(a1, bb3, acc[2*q+1][3], 0, 0, 0);
            __builtin_amdgcn_s_setprio(0);
        }
    }
}

// ---------------------------------------------------------------------------
// Stage 1: k/q/v = X @ W^T + b.  z=0 -> K(bf16), z=1 -> Q(fp32), z=2 -> V(bf16)
// 256x256 tile, 512 threads.
// ---------------------------------------------------------------------------
__global__ __launch_bounds__(512, 2) void qkv_bf16(
    const unsigned short* __restrict__ Xb,
    const unsigned short* __restrict__ Wkb, const unsigned short* __restrict__ Wqb,
    const unsigned short* __restrict__ Wvb,
    const float* __restrict__ bk, const float* __restrict__ bq, const float* __restrict__ bv,
    unsigned short* __restrict__ Kb, float* __restrict__ Qf, unsigned short* __restrict__ Vb)
{
    __shared__ unsigned short As[4 * 8192];
    __shared__ unsigned short Bs[4 * 8192];
    const int z = blockIdx.z;
    const unsigned short* W; const float* bias;
    if (z == 0)      { W = Wkb; bias = bk; }
    else if (z == 1) { W = Wqb; bias = bq; }
    else             { W = Wvb; bias = bv; }

    const long m0 = (long)blockIdx.x * 256, n0 = (long)blockIdx.y * 256;
    f32x4 acc[8][4];
    #pragma unroll
    for (int i = 0; i < 8; ++i)
        #pragma unroll
        for (int j = 0; j < 4; ++j) acc[i][j] = (f32x4){0.f, 0.f, 0.f, 0.f};

    gemm_core256(Xb, W, DD, DD, DD, m0, n0, As, Bs, acc);

    const int t = threadIdx.x, wave = t >> 6, lane = t & 63;
    const int wm = (wave >> 2) * 128, wn = (wave & 3) * 64;
    const int quad = lane >> 4, l16 = lane & 15;
    #pragma unroll
    for (int i = 0; i < 8; ++i)
        #pragma unroll
        for (int j = 0; j < 4; ++j) {
            const long col = n0 + wn + j * 16 + l16;
            const float bcol = bias[col];
            #pragma unroll
            for (int r = 0; r < 4; ++r) {
                const long row = m0 + wm + i * 16 + quad * 4 + r;
                const size_t idx = (size_t)row * DD + col;
                const float v = acc[i][j][r] + bcol;
                if (z == 1)      Qf[idx] = v;
                else if (z == 0) Kb[idx] = f2bf(v);
                else             Vb[idx] = f2bf(v);
            }
        }
}

// ---------------------------------------------------------------------------
// Stage 2: scoresT[e,d] = (1/32) * sum_s Vt[e,s] * Kt[d,s]  -> bf16
// (kept on 128x128 core: M=N=1024 gives only 128 blocks at 256^2 -> underfill)
// ---------------------------------------------------------------------------
__global__ __launch_bounds__(256, 2) void scores_bf16(
    const unsigned short* __restrict__ Vt, const unsigned short* __restrict__ Kt,
    unsigned short* __restrict__ Sh)
{
    __shared__ unsigned short As[128 * 32], Bs[128 * 32];
    const int b = blockIdx.z;
    const size_t tofs = (size_t)b * SS * DD;
    const long m0 = (long)blockIdx.x * 128, n0 = (long)blockIdx.y * 128;

    f32x4 acc[4][4];
    #pragma unroll
    for (int i = 0; i < 4; ++i)
        #pragma unroll
        for (int j = 0; j < 4; ++j) acc[i][j] = (f32x4){0.f, 0.f, 0.f, 0.f};

    gemm_core1(Vt + tofs, Kt + tofs, SS, SS, SS, m0, n0, As, Bs, acc);

    const int t = threadIdx.x, wave = t >> 6, lane = t & 63;
    const int wm = (wave & 1) * 64, wn = (wave >> 1) * 64;
    const int quad = lane >> 4, l16 = lane & 15;
    const size_t bofs = (size_t)b * DD * DD;
    #pragma unroll
    for (int i = 0; i < 4; ++i)
        #pragma unroll
        for (int j = 0; j < 4; ++j) {
            const long col = n0 + wn + j * 16 + l16;
            #pragma unroll
            for (int r = 0; r < 4; ++r) {
                const long row = m0 + wm + i * 16 + quad * 4 + r;
                Sh[bofs + (size_t)row * DD + col] = f2bf(acc[i][j][r] * 0.03125f);
            }
        }
}

// ---------------------------------------------------------------------------
// Stage 4: out[s,e] = (1/32) * sum_d P[s,d] * scoresT[e,d]   (256x256 tile)
// ---------------------------------------------------------------------------
__global__ __launch_bounds__(512, 2) void out_bf16(
    const unsigned short* __restrict__ Ph, const unsigned short* __restrict__ Sh,
    float* __restrict__ O)
{
    __shared__ unsigned short As[4 * 8192];
    __shared__ unsigned short Bs[4 * 8192];
    const long m0 = (long)blockIdx.x * 256, n0 = (long)blockIdx.y * 256;
    const int b = (int)(m0 >> 12);                // batch within group
    const size_t bofs = (size_t)b * DD * DD;

    f32x4 acc[8][4];
    #pragma unroll
    for (int i = 0; i < 8; ++i)
        #pragma unroll
        for (int j = 0; j < 4; ++j) acc[i][j] = (f32x4){0.f, 0.f, 0.f, 0.f};

    gemm_core256(Ph, Sh + bofs, DD, DD, DD, m0, n0, As, Bs, acc);

    const int t = threadIdx.x, wave = t >> 6, lane = t & 63;
    const int wm = (wave >> 2) * 128, wn = (wave & 3) * 64;
    const int quad = lane >> 4, l16 = lane & 15;
    #pragma unroll
    for (int i = 0; i < 8; ++i)
        #pragma unroll
        for (int j = 0; j < 4; ++j) {
            const long col = n0 + wn + j * 16 + l16;
            #pragma unroll
            for (int r = 0; r < 4; ++r) {
                const long row = m0 + wm + i * 16 + quad * 4 + r;
                O[(size_t)row * DD + col] = acc[i][j][r] * 0.03125f;
            }
        }
}

// ---------------------------------------------------------------------------
// fp32 -> bf16 cast (float4 in / ushort4 out)
// ---------------------------------------------------------------------------
__global__ __launch_bounds__(256) void cast_bf16(
    const float4* __restrict__ in, unsigned short* __restrict__ h, long n4)
{
    const long i = (long)blockIdx.x * 256 + threadIdx.x;
    if (i >= n4) return;
    const float4 v = in[i];
    ushort4 hh;
    hh.x = f2bf(v.x); hh.y = f2bf(v.y); hh.z = f2bf(v.z); hh.w = f2bf(v.w);
    *(ushort4*)(h + i * 4) = hh;
}

// ---------------------------------------------------------------------------
// bf16 [S,D] -> [D,S] tile transpose; z = batch*2 + {K,V}
// ---------------------------------------------------------------------------
__global__ __launch_bounds__(256) void transpose2(
    const unsigned short* __restrict__ Kb, const unsigned short* __restrict__ Vb,
    unsigned short* __restrict__ Kt, unsigned short* __restrict__ Vt)
{
    __shared__ unsigned short tile[64][65];
    const int z = blockIdx.z, b = z >> 1, sel = z & 1;
    const size_t bofs = (size_t)b * SS * DD;
    const unsigned short* in = (sel == 0 ? Kb : Vb) + bofs;
    unsigned short* outp     = (sel == 0 ? Kt : Vt) + bofs;

    const int s0 = blockIdx.x * 64, d0 = blockIdx.y * 64;
    const int t = threadIdx.x;
    const int c4 = t & 15, rbase = t >> 4;

    #pragma unroll
    for (int j = 0; j < 4; ++j) {
        const int r = j * 16 + rbase;                       // s_local
        const ushort4 v = *(const ushort4*)(in + (size_t)(s0 + r) * DD + d0 + c4 * 4);
        tile[r][c4 * 4 + 0] = v.x; tile[r][c4 * 4 + 1] = v.y;
        tile[r][c4 * 4 + 2] = v.z; tile[r][c4 * 4 + 3] = v.w;
    }
    __syncthreads();
    #pragma unroll
    for (int j = 0; j < 4; ++j) {
        const int rr = j * 16 + rbase;                      // d_local
        ushort4 v;
        v.x = tile[c4 * 4 + 0][rr]; v.y = tile[c4 * 4 + 1][rr];
        v.z = tile[c4 * 4 + 2][rr]; v.w = tile[c4 * 4 + 3][rr];
        *(ushort4*)(outp + (size_t)(d0 + rr) * SS + s0 + c4 * 4) = v;
    }
}

// ---------------------------------------------------------------------------
// Softmax over seq axis, parallelized: partial (per 512-row chunk) ->
// combine -> write (exp * inv_sum as bf16).
// ---------------------------------------------------------------------------
__global__ __launch_bounds__(256) void smax_partial(
    const float* __restrict__ Qf, float* __restrict__ Pm, float* __restrict__ Pl)
{
    __shared__ float sm[4][64], sl[4][64];
    const int t = threadIdx.x, tx = t & 63, ty = t >> 6;
    const int g = blockIdx.z;
    const int d = blockIdx.x * 64 + tx;
    const int s0 = blockIdx.y * 512 + ty * 128;
    const float* base = Qf + (size_t)g * SS * DD + (size_t)s0 * DD + d;

    float m = -INFINITY, l = 0.f;
    for (int r = 0; r < 128; ++r) {
        const float x = base[(size_t)r * DD];
        const float nm = fmaxf(m, x);
        l = l * __expf(m - nm) + __expf(x - nm);
        m = nm;
    }
    sm[ty][tx] = m; sl[ty][tx] = l;
    __syncthreads();
    if (t < 64) {
        float M = sm[0][t], L = sl[0][t];
        #pragma unroll
        for (int c = 1; c < 4; ++c) {
            const float mc = sm[c][t], lc = sl[c][t];
            const float nm = fmaxf(M, mc);
            L = L * __expf(M - nm) + lc * __expf(mc - nm);
            M = nm;
        }
        const size_t o = ((size_t)g * 8 + blockIdx.y) * DD + blockIdx.x * 64 + t;
        Pm[o] = M; Pl[o] = L;
    }
}

__global__ __launch_bounds__(256) void smax_combine(
    const float* __restrict__ Pm, const float* __restrict__ Pl,
    float* __restrict__ Fm, float* __restrict__ Fl)
{
    const int g = blockIdx.y;
    const int d = blockIdx.x * 256 + threadIdx.x;
    float M = -INFINITY, L = 0.f;
    #pragma unroll
    for (int c = 0; c < 8; ++c) {
        const size_t o = ((size_t)g * 8 + c) * DD + d;
        const float mc = Pm[o], lc = Pl[o];
        const float nm = fmaxf(M, mc);
        L = L * __expf(M - nm) + lc * __expf(mc - nm);
        M = nm;
    }
    Fm[(size_t)g * DD + d] = M;
    Fl[(size_t)g * DD + d] = 1.f / L;
}

__global__ __launch_bounds__(256) void smax_write(
    const float* __restrict__ Qf, const float* __restrict__ Fm,
    const float* __restrict__ Fl, unsigned short* __restrict__ Ph)
{
    const int t = threadIdx.x, tx = t & 63, ty = t >> 6;
    const int g = blockIdx.z;
    const int d = blockIdx.x * 64 + tx;
    const int s0 = blockIdx.y * 512 + ty * 128;
    const float M  = Fm[(size_t)g * DD + d];
    const float IL = Fl[(size_t)g * DD + d];
    const float* base = Qf + (size_t)g * SS * DD + (size_t)s0 * DD + d;
    unsigned short* pb = Ph + (size_t)g * SS * DD + (size_t)s0 * DD + d;
    for (int r = 0; r < 128; ++r) {
        const float p = __expf(base[(size_t)r * DD] - M) * IL;
        pb[(size_t)r * DD] = f2bf(p);
    }
}

// ---------------------------------------------------------------------------
extern "C" void kernel_launch(void* const* d_in, const int* in_sizes, int n_in,
                              void* d_out, int out_size, void* d_ws, size_t ws_size,
                              hipStream_t stream)
{
    (void)in_sizes; (void)n_in; (void)out_size;
    const float* X  = (const float*)d_in[0];
    const float* Wk = (const float*)d_in[1];
    const float* bk = (const float*)d_in[2];
    const float* Wq = (const float*)d_in[3];
    const float* bq = (const float*)d_in[4];
    const float* Wv = (const float*)d_in[5];
    const float* bv = (const float*)d_in[6];
    float* out = (float*)d_out;

    const size_t SD = (size_t)SS * DD;           // 4M elems
    const size_t WN = (size_t)DD * DD;           // 1M elems

    // per-batch ws bytes: Xb(2)+Kb(2)+Vb(2)+Qf(4)+Kt(2)+Vt(2) [*SD] + Sh(2*WN)
    // + softmax scratch (~70KB); Ph aliases Xb.
    const size_t perBatch = 14 * SD + 2 * WN + (size_t)(1 << 17);
    const size_t fixed = 3 * WN * 2 + (size_t)(1 << 20);
    size_t usable = (ws_size > fixed) ? ws_size - fixed : 0;
    int G = (int)(usable / perBatch);
    if (G < 1) G = 1;
    if (G > BB) G = BB;

    char* p = (char*)d_ws;
    auto alloc = [&](size_t bytes) {
        char* q = p;
        p += (bytes + 255) & ~(size_t)255;
        return q;
    };
    unsigned short* Wkb = (unsigned short*)alloc(WN * 2);
    unsigned short* Wqb = (unsigned short*)alloc(WN * 2);
    unsigned short* Wvb = (unsigned short*)alloc(WN * 2);
    unsigned short* Xb  = (unsigned short*)alloc((size_t)G * SD * 2);
    unsigned short* Kb  = (unsigned short*)alloc((size_t)G * SD * 2);
    unsigned short* Vb  = (unsigned short*)alloc((size_t)G * SD * 2);
    float*          Qf  = (float*)         alloc((size_t)G * SD * 4);
    unsigned short* Kt  = (unsigned short*)alloc((size_t)G * SD * 2);
    unsigned short* Vt  = (unsigned short*)alloc((size_t)G * SD * 2);
    unsigned short* Sh  = (unsigned short*)alloc((size_t)G * WN * 2);
    float*          Pm  = (float*)alloc((size_t)G * 8 * DD * 4);
    float*          Pl  = (float*)alloc((size_t)G * 8 * DD * 4);
    float*          Fm  = (float*)alloc((size_t)G * DD * 4);
    float*          Fl  = (float*)alloc((size_t)G * DD * 4);
    unsigned short* Ph  = Xb;   // X dead after stage 1

    // weights: cast once per call
    cast_bf16<<<dim3((unsigned)(WN / 4 / 256)), 256, 0, stream>>>((const float4*)Wk, Wkb, (long)(WN / 4));
    cast_bf16<<<dim3((unsigned)(WN / 4 / 256)), 256, 0, stream>>>((const float4*)Wq, Wqb, (long)(WN / 4));
    cast_bf16<<<dim3((unsigned)(WN / 4 / 256)), 256, 0, stream>>>((const float4*)Wv, Wvb, (long)(WN / 4));

    for (int b0 = 0; b0 < BB; b0 += G) {
        const int Gc = (b0 + G <= BB) ? G : (BB - b0);
        const float* Xg = X + (size_t)b0 * SD;

        const long n4 = (long)((size_t)Gc * SD / 4);
        cast_bf16<<<dim3((unsigned)((n4 + 255) / 256)), 256, 0, stream>>>(
            (const float4*)Xg, Xb, n4);

        qkv_bf16<<<dim3(Gc * SS / 256, DD / 256, 3), 512, 0, stream>>>(
            Xb, Wkb, Wqb, Wvb, bk, bq, bv, Kb, Qf, Vb);

        transpose2<<<dim3(SS / 64, DD / 64, Gc * 2), 256, 0, stream>>>(
            Kb, Vb, Kt, Vt);

        smax_partial<<<dim3(DD / 64, SS / 512, Gc), 256, 0, stream>>>(Qf, Pm, Pl);
        smax_combine<<<dim3(DD / 256, Gc), 256, 0, stream>>>(Pm, Pl, Fm, Fl);
        smax_write<<<dim3(DD / 64, SS / 512, Gc), 256, 0, stream>>>(Qf, Fm, Fl, Ph);

        scores_bf16<<<dim3(DD / 128, DD / 128, Gc), 256, 0, stream>>>(Vt, Kt, Sh);

        out_bf16<<<dim3(Gc * SS / 256, DD / 256), 512, 0, stream>>>(
            Ph, Sh, out + (size_t)b0 * SD);
    }
}